// Round 1
// baseline (957.764 us; speedup 1.0000x reference)
//
#include <hip/hip_runtime.h>
#include <math.h>

#define FEAT 120
#define HCNT 4

// norm_act: y = sigmoid(n) * x / n, n = sqrt(sum x^2 + EPS^2), EPS=1e-5
__device__ __forceinline__ float nact_scale(float sumsq) {
    float n = sqrtf(sumsq + 1e-10f);
    float sig = 1.0f / (1.0f + expf(-n));
    return sig / n;
}

// scales: o3_linear fan-in norms
#define INV_S32 0.17677669529663687f   // 1/sqrt(32)
#define INV_S16 0.25f                  // 1/sqrt(16)
#define INV_S8  0.35355339059327373f   // 1/sqrt(8)
// tp_dot scales: 1/(sqrt(2l+1)*sqrt(fan)), fan = 32*32*1+16*16*3+8*8*5 = 2112
#define S_IR0 0.02175970668223486f     // 1/sqrt(2112)
#define S_IR1 0.012562972567021898f    // /sqrt(3)
#define S_IR2 0.009731317442393031f    // /sqrt(5)

__global__ __launch_bounds__(256) void zero_kernel(float* __restrict__ z, int n) {
    int i = blockIdx.x * 256 + threadIdx.x;
    if (i < n) z[i] = 0.0f;
}

// One wave per node. Computes q,k,v = norm_act(o3_linear(x, W*)), writes
// knode, vnode, out=vnode, and tq[n][h][f] = sum_i q[i,m]*Wd[i,j,h]*scale.
__global__ __launch_bounds__(256) void node_kernel(
    const float* __restrict__ x,
    const float* __restrict__ Wq0, const float* __restrict__ Wq1, const float* __restrict__ Wq2,
    const float* __restrict__ Wk0, const float* __restrict__ Wk1, const float* __restrict__ Wk2,
    const float* __restrict__ Wv0, const float* __restrict__ Wv1, const float* __restrict__ Wv2,
    const float* __restrict__ Wd0, const float* __restrict__ Wd1, const float* __restrict__ Wd2,
    float* __restrict__ knode, float* __restrict__ vnode, float* __restrict__ tq,
    float* __restrict__ out, int N)
{
    __shared__ float sWq0[1024], sWq1[256], sWq2[64];
    __shared__ float sWk0[1024], sWk1[256], sWk2[64];
    __shared__ float sWv0[1024], sWv1[256], sWv2[64];
    __shared__ float4 sWd0[1024];  // 32*32*4 floats
    __shared__ float4 sWd1[256];   // 16*16*4 floats
    __shared__ float4 sWd2[64];    // 8*8*4 floats
    __shared__ float qs[4][FEAT];

    int t = threadIdx.x;
    for (int i = t; i < 1024; i += 256) {
        sWq0[i] = Wq0[i]; sWk0[i] = Wk0[i]; sWv0[i] = Wv0[i];
        sWd0[i] = ((const float4*)Wd0)[i];
    }
    for (int i = t; i < 256; i += 256) {
        sWq1[i] = Wq1[i]; sWk1[i] = Wk1[i]; sWv1[i] = Wv1[i];
        sWd1[i] = ((const float4*)Wd1)[i];
    }
    if (t < 64) {
        sWq2[t] = Wq2[t]; sWk2[t] = Wk2[t]; sWv2[t] = Wv2[t];
        sWd2[t] = ((const float4*)Wd2)[t];
    }
    __syncthreads();

    int lane = t & 63, wid = t >> 6;
    int ngrp = (N + 3) >> 2;
    for (int grp = blockIdx.x; grp < ngrp; grp += gridDim.x) {
        int node = grp * 4 + wid;
        bool active = node < N;
        if (active) {
            const float* xr = x + (size_t)node * FEAT;
            float* kr = knode + (size_t)node * FEAT;
            float* vr = vnode + (size_t)node * FEAT;
            float* orow = out + (size_t)node * FEAT;
            if (lane < 32) {
                int o = lane;
                float q = 0, k = 0, v = 0;
                #pragma unroll 8
                for (int i = 0; i < 32; i++) {
                    float xi = xr[i];
                    q = fmaf(xi, sWq0[i * 32 + o], q);
                    k = fmaf(xi, sWk0[i * 32 + o], k);
                    v = fmaf(xi, sWv0[i * 32 + o], v);
                }
                q *= INV_S32; k *= INV_S32; v *= INV_S32;
                q *= nact_scale(q * q);
                k *= nact_scale(k * k);
                v *= nact_scale(v * v);
                kr[o] = k; vr[o] = v; orow[o] = v; qs[wid][o] = q;
            } else if (lane < 48) {
                int o = lane - 32;
                float q[3] = {0,0,0}, k[3] = {0,0,0}, v[3] = {0,0,0};
                for (int i = 0; i < 16; i++) {
                    float wq = sWq1[i * 16 + o], wk = sWk1[i * 16 + o], wv = sWv1[i * 16 + o];
                    #pragma unroll
                    for (int c = 0; c < 3; c++) {
                        float xi = xr[32 + i * 3 + c];
                        q[c] = fmaf(xi, wq, q[c]);
                        k[c] = fmaf(xi, wk, k[c]);
                        v[c] = fmaf(xi, wv, v[c]);
                    }
                }
                float nq = 0, nk = 0, nv = 0;
                #pragma unroll
                for (int c = 0; c < 3; c++) {
                    q[c] *= INV_S16; k[c] *= INV_S16; v[c] *= INV_S16;
                    nq += q[c]*q[c]; nk += k[c]*k[c]; nv += v[c]*v[c];
                }
                float sq = nact_scale(nq), sk = nact_scale(nk), sv = nact_scale(nv);
                #pragma unroll
                for (int c = 0; c < 3; c++) {
                    int f = 32 + o * 3 + c;
                    float qq = q[c]*sq, kk = k[c]*sk, vv = v[c]*sv;
                    kr[f] = kk; vr[f] = vv; orow[f] = vv; qs[wid][f] = qq;
                }
            } else if (lane < 56) {
                int o = lane - 48;
                float q[5] = {0,0,0,0,0}, k[5] = {0,0,0,0,0}, v[5] = {0,0,0,0,0};
                for (int i = 0; i < 8; i++) {
                    float wq = sWq2[i * 8 + o], wk = sWk2[i * 8 + o], wv = sWv2[i * 8 + o];
                    #pragma unroll
                    for (int c = 0; c < 5; c++) {
                        float xi = xr[80 + i * 5 + c];
                        q[c] = fmaf(xi, wq, q[c]);
                        k[c] = fmaf(xi, wk, k[c]);
                        v[c] = fmaf(xi, wv, v[c]);
                    }
                }
                float nq = 0, nk = 0, nv = 0;
                #pragma unroll
                for (int c = 0; c < 5; c++) {
                    q[c] *= INV_S8; k[c] *= INV_S8; v[c] *= INV_S8;
                    nq += q[c]*q[c]; nk += k[c]*k[c]; nv += v[c]*v[c];
                }
                float sq = nact_scale(nq), sk = nact_scale(nk), sv = nact_scale(nv);
                #pragma unroll
                for (int c = 0; c < 5; c++) {
                    int f = 80 + o * 5 + c;
                    float qq = q[c]*sq, kk = k[c]*sk, vv = v[c]*sv;
                    kr[f] = kk; vr[f] = vv; orow[f] = vv; qs[wid][f] = qq;
                }
            }
        }
        __syncthreads();
        if (active) {
            float* tr = tq + (size_t)node * (HCNT * FEAT);
            if (lane < 32) {
                int j = lane;
                float a0 = 0, a1 = 0, a2 = 0, a3 = 0;
                #pragma unroll 8
                for (int i = 0; i < 32; i++) {
                    float qi = qs[wid][i];
                    float4 w = sWd0[i * 32 + j];
                    a0 = fmaf(qi, w.x, a0); a1 = fmaf(qi, w.y, a1);
                    a2 = fmaf(qi, w.z, a2); a3 = fmaf(qi, w.w, a3);
                }
                tr[0 * FEAT + j] = a0 * S_IR0;
                tr[1 * FEAT + j] = a1 * S_IR0;
                tr[2 * FEAT + j] = a2 * S_IR0;
                tr[3 * FEAT + j] = a3 * S_IR0;
            } else if (lane < 48) {
                int j = lane - 32;
                float a[4][3] = {};
                for (int i = 0; i < 16; i++) {
                    float4 w = sWd1[i * 16 + j];
                    #pragma unroll
                    for (int c = 0; c < 3; c++) {
                        float qi = qs[wid][32 + i * 3 + c];
                        a[0][c] = fmaf(qi, w.x, a[0][c]);
                        a[1][c] = fmaf(qi, w.y, a[1][c]);
                        a[2][c] = fmaf(qi, w.z, a[2][c]);
                        a[3][c] = fmaf(qi, w.w, a[3][c]);
                    }
                }
                #pragma unroll
                for (int h = 0; h < 4; h++)
                    #pragma unroll
                    for (int c = 0; c < 3; c++)
                        tr[h * FEAT + 32 + j * 3 + c] = a[h][c] * S_IR1;
            } else if (lane < 56) {
                int j = lane - 48;
                float a[4][5] = {};
                for (int i = 0; i < 8; i++) {
                    float4 w = sWd2[i * 8 + j];
                    #pragma unroll
                    for (int c = 0; c < 5; c++) {
                        float qi = qs[wid][80 + i * 5 + c];
                        a[0][c] = fmaf(qi, w.x, a[0][c]);
                        a[1][c] = fmaf(qi, w.y, a[1][c]);
                        a[2][c] = fmaf(qi, w.z, a[2][c]);
                        a[3][c] = fmaf(qi, w.w, a[3][c]);
                    }
                }
                #pragma unroll
                for (int h = 0; h < 4; h++)
                    #pragma unroll
                    for (int c = 0; c < 5; c++)
                        tr[h * FEAT + 80 + j * 5 + c] = a[h][c] * S_IR2;
            }
        }
        __syncthreads();
    }
}

// One wave per edge: dot(tq[dst,h,:], knode[src,:]) for h=0..3, exp+mean,
// store per-edge exp and atomically accumulate z[dst].
__global__ __launch_bounds__(256) void edge_dot_kernel(
    const float* __restrict__ tq, const float* __restrict__ knode,
    const int* __restrict__ edge_dst, const int* __restrict__ edge_src,
    float* __restrict__ expb, float* __restrict__ z, int E)
{
    int e = (blockIdx.x * 256 + threadIdx.x) >> 6;
    int lane = threadIdx.x & 63;
    if (e >= E) return;
    int d = edge_dst[e], s = edge_src[e];
    const float* kr = knode + (size_t)s * FEAT;
    const float* tr = tq + (size_t)d * (HCNT * FEAT);
    float k0 = kr[lane];
    float k1 = (lane < 56) ? kr[64 + lane] : 0.0f;
    float dh[4];
    #pragma unroll
    for (int h = 0; h < 4; h++) {
        float t0 = tr[h * FEAT + lane];
        float t1 = (lane < 56) ? tr[h * FEAT + 64 + lane] : 0.0f;
        float p = t0 * k0 + t1 * k1;
        #pragma unroll
        for (int off = 32; off > 0; off >>= 1) p += __shfl_xor(p, off, 64);
        dh[h] = p;
    }
    if (lane == 0) {
        float ex = 0.25f * (expf(dh[0]) + expf(dh[1]) + expf(dh[2]) + expf(dh[3]));
        expb[e] = ex;
        atomicAdd(&z[d], ex);
    }
}

// One wave per edge: out[dst] += sqrt(exp/z[dst]) * vnode[src]
__global__ __launch_bounds__(256) void edge_scatter_kernel(
    const float* __restrict__ vnode, const float* __restrict__ expb,
    const float* __restrict__ z,
    const int* __restrict__ edge_dst, const int* __restrict__ edge_src,
    float* __restrict__ out, int E)
{
    int e = (blockIdx.x * 256 + threadIdx.x) >> 6;
    int lane = threadIdx.x & 63;
    if (e >= E) return;
    int d = edge_dst[e], s = edge_src[e];
    float w = sqrtf(expb[e] / z[d]);
    const float* vr = vnode + (size_t)s * FEAT;
    float* orow = out + (size_t)d * FEAT;
    atomicAdd(&orow[lane], w * vr[lane]);
    if (lane < 56) atomicAdd(&orow[64 + lane], w * vr[64 + lane]);
}

extern "C" void kernel_launch(void* const* d_in, const int* in_sizes, int n_in,
                              void* d_out, int out_size, void* d_ws, size_t ws_size,
                              hipStream_t stream) {
    const float* x   = (const float*)d_in[0];
    const float* Wq0 = (const float*)d_in[1];
    const float* Wq1 = (const float*)d_in[2];
    const float* Wq2 = (const float*)d_in[3];
    const float* Wk0 = (const float*)d_in[4];
    const float* Wk1 = (const float*)d_in[5];
    const float* Wk2 = (const float*)d_in[6];
    const float* Wv0 = (const float*)d_in[7];
    const float* Wv1 = (const float*)d_in[8];
    const float* Wv2 = (const float*)d_in[9];
    const float* Wd0 = (const float*)d_in[10];
    const float* Wd1 = (const float*)d_in[11];
    const float* Wd2 = (const float*)d_in[12];
    const int* edge_dst = (const int*)d_in[13];
    const int* edge_src = (const int*)d_in[14];
    float* out = (float*)d_out;

    int N = in_sizes[0] / FEAT;
    int E = in_sizes[13];

    float* ws = (float*)d_ws;
    float* knode = ws;                                // N*120
    float* vnode = knode + (size_t)N * FEAT;          // N*120
    float* tq    = vnode + (size_t)N * FEAT;          // N*480
    float* zbuf  = tq + (size_t)N * HCNT * FEAT;      // N
    float* expb  = zbuf + N;                          // E

    zero_kernel<<<(N + 255) / 256, 256, 0, stream>>>(zbuf, N);
    node_kernel<<<1024, 256, 0, stream>>>(
        x, Wq0, Wq1, Wq2, Wk0, Wk1, Wk2, Wv0, Wv1, Wv2, Wd0, Wd1, Wd2,
        knode, vnode, tq, out, N);
    int eb = (E + 3) / 4;   // 4 waves (edges) per 256-thread block
    edge_dot_kernel<<<eb, 256, 0, stream>>>(tq, knode, edge_dst, edge_src, expb, zbuf, E);
    edge_scatter_kernel<<<eb, 256, 0, stream>>>(vnode, expb, zbuf, edge_dst, edge_src, out, E);
}

// Round 2
// 557.605 us; speedup vs baseline: 1.7176x; 1.7176x over previous
//
#include <hip/hip_runtime.h>
#include <math.h>

#define FEAT 120
#define HCNT 4

__device__ __forceinline__ float nact_scale(float sumsq) {
    float n = sqrtf(sumsq + 1e-10f);
    float sig = 1.0f / (1.0f + expf(-n));
    return sig / n;
}

#define INV_S32 0.17677669529663687f   // 1/sqrt(32)
#define INV_S16 0.25f                  // 1/sqrt(16)
#define INV_S8  0.35355339059327373f   // 1/sqrt(8)
// tp_dot scales: 1/(sqrt(2l+1)*sqrt(fan)), fan = 32*32 + 16*16*3 + 8*8*5 = 2112
#define S_IR0 0.02175970668223486f
#define S_IR1 0.012562972567021898f
#define S_IR2 0.009731317442393031f

// ---------------- counting sort by dst ----------------

__global__ __launch_bounds__(256) void zero_int_kernel(int* __restrict__ p, int n) {
    int i = blockIdx.x * 256 + threadIdx.x;
    if (i < n) p[i] = 0;
}

__global__ __launch_bounds__(256) void hist_kernel(const int* __restrict__ dst,
                                                   int* __restrict__ cnt, int E) {
    int e = blockIdx.x * 256 + threadIdx.x;
    if (e < E) atomicAdd(&cnt[dst[e]], 1);
}

// per-block exclusive scan of cnt -> excl (within-block), block totals -> bsum
__global__ __launch_bounds__(256) void scan_block_kernel(const int* __restrict__ cnt,
                                                         int* __restrict__ excl,
                                                         int* __restrict__ bsum, int n) {
    __shared__ int s[256];
    int t = threadIdx.x;
    int i = blockIdx.x * 256 + t;
    int v = (i < n) ? cnt[i] : 0;
    s[t] = v;
    __syncthreads();
    for (int off = 1; off < 256; off <<= 1) {
        int add = (t >= off) ? s[t - off] : 0;
        __syncthreads();
        s[t] += add;
        __syncthreads();
    }
    if (i < n) excl[i] = s[t] - v;
    if (t == 255) bsum[blockIdx.x] = s[255];
}

// single block: exclusive scan of bsum[0..nb)
__global__ __launch_bounds__(256) void scan_sums_kernel(int* __restrict__ bsum, int nb) {
    __shared__ int s[256];
    int t = threadIdx.x;
    int v = (t < nb) ? bsum[t] : 0;
    s[t] = v;
    __syncthreads();
    for (int off = 1; off < 256; off <<= 1) {
        int add = (t >= off) ? s[t - off] : 0;
        __syncthreads();
        s[t] += add;
        __syncthreads();
    }
    if (t < nb) bsum[t] = s[t] - v;
}

// offsets[i] = excl[i] + bsum[i>>8]; cursor[i] = offsets[i]; offsets[n] = E
__global__ __launch_bounds__(256) void add_offsets_kernel(int* __restrict__ offsets,
                                                          const int* __restrict__ bsum,
                                                          int* __restrict__ cursor,
                                                          int n, int E) {
    int i = blockIdx.x * 256 + threadIdx.x;
    if (i < n) {
        int off = offsets[i] + bsum[i >> 8];
        offsets[i] = off;
        cursor[i] = off;
    }
    if (i == 0) offsets[n] = E;
}

__global__ __launch_bounds__(256) void scatter_kernel(const int* __restrict__ dst,
                                                      const int* __restrict__ src,
                                                      int* __restrict__ cursor,
                                                      int* __restrict__ ssrc, int E) {
    int e = blockIdx.x * 256 + threadIdx.x;
    if (e < E) {
        int pos = atomicAdd(&cursor[dst[e]], 1);
        ssrc[pos] = src[e];
    }
}

// ---------------- node kernel: q,k,v = norm_act(o3_linear(x)) ----------------

__global__ __launch_bounds__(256) void node_kernel(
    const float* __restrict__ x,
    const float* __restrict__ Wq0, const float* __restrict__ Wq1, const float* __restrict__ Wq2,
    const float* __restrict__ Wk0, const float* __restrict__ Wk1, const float* __restrict__ Wk2,
    const float* __restrict__ Wv0, const float* __restrict__ Wv1, const float* __restrict__ Wv2,
    float* __restrict__ qnode, float* __restrict__ knode, float* __restrict__ vnode, int N)
{
    __shared__ float sWq0[1024], sWq1[256], sWq2[64];
    __shared__ float sWk0[1024], sWk1[256], sWk2[64];
    __shared__ float sWv0[1024], sWv1[256], sWv2[64];

    int t = threadIdx.x;
    for (int i = t; i < 1024; i += 256) { sWq0[i] = Wq0[i]; sWk0[i] = Wk0[i]; sWv0[i] = Wv0[i]; }
    if (t < 256) { sWq1[t] = Wq1[t]; sWk1[t] = Wk1[t]; sWv1[t] = Wv1[t]; }
    if (t < 64)  { sWq2[t] = Wq2[t]; sWk2[t] = Wk2[t]; sWv2[t] = Wv2[t]; }
    __syncthreads();

    int lane = t & 63, wid = t >> 6;
    int node = blockIdx.x * 4 + wid;
    if (node >= N) return;

    const float* xr = x + (size_t)node * FEAT;
    float* qr = qnode + (size_t)node * FEAT;
    float* kr = knode + (size_t)node * FEAT;
    float* vr = vnode + (size_t)node * FEAT;

    if (lane < 32) {
        int o = lane;
        float q = 0, k = 0, v = 0;
        #pragma unroll 8
        for (int i = 0; i < 32; i++) {
            float xi = xr[i];
            q = fmaf(xi, sWq0[i * 32 + o], q);
            k = fmaf(xi, sWk0[i * 32 + o], k);
            v = fmaf(xi, sWv0[i * 32 + o], v);
        }
        q *= INV_S32; k *= INV_S32; v *= INV_S32;
        q *= nact_scale(q * q);
        k *= nact_scale(k * k);
        v *= nact_scale(v * v);
        qr[o] = q; kr[o] = k; vr[o] = v;
    } else if (lane < 48) {
        int o = lane - 32;
        float q[3] = {0,0,0}, k[3] = {0,0,0}, v[3] = {0,0,0};
        for (int i = 0; i < 16; i++) {
            float wq = sWq1[i * 16 + o], wk = sWk1[i * 16 + o], wv = sWv1[i * 16 + o];
            #pragma unroll
            for (int c = 0; c < 3; c++) {
                float xi = xr[32 + i * 3 + c];
                q[c] = fmaf(xi, wq, q[c]);
                k[c] = fmaf(xi, wk, k[c]);
                v[c] = fmaf(xi, wv, v[c]);
            }
        }
        float nq = 0, nk = 0, nv = 0;
        #pragma unroll
        for (int c = 0; c < 3; c++) {
            q[c] *= INV_S16; k[c] *= INV_S16; v[c] *= INV_S16;
            nq += q[c]*q[c]; nk += k[c]*k[c]; nv += v[c]*v[c];
        }
        float sq = nact_scale(nq), sk = nact_scale(nk), sv = nact_scale(nv);
        #pragma unroll
        for (int c = 0; c < 3; c++) {
            int f = 32 + o * 3 + c;
            qr[f] = q[c]*sq; kr[f] = k[c]*sk; vr[f] = v[c]*sv;
        }
    } else if (lane < 56) {
        int o = lane - 48;
        float q[5] = {0,0,0,0,0}, k[5] = {0,0,0,0,0}, v[5] = {0,0,0,0,0};
        for (int i = 0; i < 8; i++) {
            float wq = sWq2[i * 8 + o], wk = sWk2[i * 8 + o], wv = sWv2[i * 8 + o];
            #pragma unroll
            for (int c = 0; c < 5; c++) {
                float xi = xr[80 + i * 5 + c];
                q[c] = fmaf(xi, wq, q[c]);
                k[c] = fmaf(xi, wk, k[c]);
                v[c] = fmaf(xi, wv, v[c]);
            }
        }
        float nq = 0, nk = 0, nv = 0;
        #pragma unroll
        for (int c = 0; c < 5; c++) {
            q[c] *= INV_S8; k[c] *= INV_S8; v[c] *= INV_S8;
            nq += q[c]*q[c]; nk += k[c]*k[c]; nv += v[c]*v[c];
        }
        float sq = nact_scale(nq), sk = nact_scale(nk), sv = nact_scale(nv);
        #pragma unroll
        for (int c = 0; c < 5; c++) {
            int f = 80 + o * 5 + c;
            qr[f] = q[c]*sq; kr[f] = k[c]*sk; vr[f] = v[c]*sv;
        }
    }
}

// ---------------- fused per-dst edge kernel ----------------

__device__ __forceinline__ void tq_at(int f, const float* __restrict__ qr,
                                      const float4* __restrict__ sWd0,
                                      const float4* __restrict__ sWd1,
                                      const float4* __restrict__ sWd2,
                                      float t[4]) {
    float a0 = 0, a1 = 0, a2 = 0, a3 = 0;
    if (f < 32) {
        int j = f;
        #pragma unroll 8
        for (int i = 0; i < 32; i++) {
            float qi = qr[i]; float4 w = sWd0[i * 32 + j];
            a0 = fmaf(qi, w.x, a0); a1 = fmaf(qi, w.y, a1);
            a2 = fmaf(qi, w.z, a2); a3 = fmaf(qi, w.w, a3);
        }
        t[0] = a0 * S_IR0; t[1] = a1 * S_IR0; t[2] = a2 * S_IR0; t[3] = a3 * S_IR0;
    } else if (f < 80) {
        int g = f - 32, j = g / 3, m = g - j * 3;
        for (int i = 0; i < 16; i++) {
            float qi = qr[32 + i * 3 + m]; float4 w = sWd1[i * 16 + j];
            a0 = fmaf(qi, w.x, a0); a1 = fmaf(qi, w.y, a1);
            a2 = fmaf(qi, w.z, a2); a3 = fmaf(qi, w.w, a3);
        }
        t[0] = a0 * S_IR1; t[1] = a1 * S_IR1; t[2] = a2 * S_IR1; t[3] = a3 * S_IR1;
    } else if (f < FEAT) {
        int g = f - 80, j = g / 5, m = g - j * 5;
        for (int i = 0; i < 8; i++) {
            float qi = qr[80 + i * 5 + m]; float4 w = sWd2[i * 8 + j];
            a0 = fmaf(qi, w.x, a0); a1 = fmaf(qi, w.y, a1);
            a2 = fmaf(qi, w.z, a2); a3 = fmaf(qi, w.w, a3);
        }
        t[0] = a0 * S_IR2; t[1] = a1 * S_IR2; t[2] = a2 * S_IR2; t[3] = a3 * S_IR2;
    } else {
        t[0] = t[1] = t[2] = t[3] = 0.0f;
    }
}

__global__ __launch_bounds__(256) void edge_fused_kernel(
    const float* __restrict__ qnode, const float* __restrict__ knode,
    const float* __restrict__ vnode,
    const float* __restrict__ Wd0, const float* __restrict__ Wd1, const float* __restrict__ Wd2,
    const int* __restrict__ offsets, const int* __restrict__ ssrc,
    float* __restrict__ out, int N)
{
    __shared__ float4 sWd0[1024];  // 32*32 heads-vec
    __shared__ float4 sWd1[256];
    __shared__ float4 sWd2[64];
    __shared__ float qrow[4][FEAT];

    int t = threadIdx.x;
    for (int i = t; i < 1024; i += 256) sWd0[i] = ((const float4*)Wd0)[i];
    if (t < 256) sWd1[t] = ((const float4*)Wd1)[t];
    if (t < 64)  sWd2[t] = ((const float4*)Wd2)[t];
    __syncthreads();

    int lane = t & 63, wid = t >> 6;
    int node = blockIdx.x * 4 + wid;
    if (node >= N) return;

    const float* qsrc = qnode + (size_t)node * FEAT;
    qrow[wid][lane] = qsrc[lane];
    if (lane < FEAT - 64) qrow[wid][64 + lane] = qsrc[64 + lane];
    // wave-internal LDS RAW: compiler inserts lgkmcnt wait; no cross-wave sharing
    __builtin_amdgcn_wave_barrier();

    float tA[4], tB[4];
    tq_at(lane,      qrow[wid], sWd0, sWd1, sWd2, tA);
    tq_at(64 + lane, qrow[wid], sWd0, sWd1, sWd2, tB);

    int beg = offsets[node], end = offsets[node + 1];
    float zsum = 0.0f, acc0 = 0.0f, acc1 = 0.0f;
    bool hi = (lane < FEAT - 64);

    for (int p = beg; p < end; ++p) {
        int s = ssrc[p];
        const float* kr = knode + (size_t)s * FEAT;
        const float* vr = vnode + (size_t)s * FEAT;
        float k0 = kr[lane];
        float k1 = hi ? kr[64 + lane] : 0.0f;
        float v0 = vr[lane];
        float v1 = hi ? vr[64 + lane] : 0.0f;

        float d0 = fmaf(tA[0], k0, tB[0] * k1);
        float d1 = fmaf(tA[1], k0, tB[1] * k1);
        float d2 = fmaf(tA[2], k0, tB[2] * k1);
        float d3 = fmaf(tA[3], k0, tB[3] * k1);
        #pragma unroll
        for (int off = 1; off < 64; off <<= 1) {
            d0 += __shfl_xor(d0, off, 64);
            d1 += __shfl_xor(d1, off, 64);
            d2 += __shfl_xor(d2, off, 64);
            d3 += __shfl_xor(d3, off, 64);
        }
        float ex = 0.25f * (expf(d0) + expf(d1) + expf(d2) + expf(d3));
        zsum += ex;
        float w = sqrtf(ex);
        acc0 = fmaf(w, v0, acc0);
        acc1 = fmaf(w, v1, acc1);
    }

    float scale = (zsum > 0.0f) ? rsqrtf(zsum) : 0.0f;
    const float* vself = vnode + (size_t)node * FEAT;
    float* orow = out + (size_t)node * FEAT;
    orow[lane] = vself[lane] + acc0 * scale;
    if (hi) orow[64 + lane] = vself[64 + lane] + acc1 * scale;
}

// ---------------- launch ----------------

extern "C" void kernel_launch(void* const* d_in, const int* in_sizes, int n_in,
                              void* d_out, int out_size, void* d_ws, size_t ws_size,
                              hipStream_t stream) {
    const float* x   = (const float*)d_in[0];
    const float* Wq0 = (const float*)d_in[1];
    const float* Wq1 = (const float*)d_in[2];
    const float* Wq2 = (const float*)d_in[3];
    const float* Wk0 = (const float*)d_in[4];
    const float* Wk1 = (const float*)d_in[5];
    const float* Wk2 = (const float*)d_in[6];
    const float* Wv0 = (const float*)d_in[7];
    const float* Wv1 = (const float*)d_in[8];
    const float* Wv2 = (const float*)d_in[9];
    const float* Wd0 = (const float*)d_in[10];
    const float* Wd1 = (const float*)d_in[11];
    const float* Wd2 = (const float*)d_in[12];
    const int* edge_dst = (const int*)d_in[13];
    const int* edge_src = (const int*)d_in[14];
    float* out = (float*)d_out;

    int N = in_sizes[0] / FEAT;
    int E = in_sizes[13];

    float* ws = (float*)d_ws;
    float* qnode = ws;                                  // N*120
    float* knode = qnode + (size_t)N * FEAT;            // N*120
    float* vnode = knode + (size_t)N * FEAT;            // N*120
    int* offsets = (int*)(vnode + (size_t)N * FEAT);    // N+1
    int* cursor  = offsets + (N + 1);                   // N
    int* bsum    = cursor + N;                          // 256
    int* ssrc    = bsum + 256;                          // E

    int NB = (N + 255) / 256;      // 196
    int EB = (E + 255) / 256;      // 3125
    int NW = (N + 3) / 4;          // 12500 (4 waves/block)

    zero_int_kernel<<<NB, 256, 0, stream>>>(cursor, N);
    hist_kernel<<<EB, 256, 0, stream>>>(edge_dst, cursor, E);
    scan_block_kernel<<<NB, 256, 0, stream>>>(cursor, offsets, bsum, N);
    scan_sums_kernel<<<1, 256, 0, stream>>>(bsum, NB);
    add_offsets_kernel<<<NB, 256, 0, stream>>>(offsets, bsum, cursor, N, E);
    scatter_kernel<<<EB, 256, 0, stream>>>(edge_dst, edge_src, cursor, ssrc, E);

    node_kernel<<<NW, 256, 0, stream>>>(x, Wq0, Wq1, Wq2, Wk0, Wk1, Wk2,
                                        Wv0, Wv1, Wv2, qnode, knode, vnode, N);
    edge_fused_kernel<<<NW, 256, 0, stream>>>(qnode, knode, vnode, Wd0, Wd1, Wd2,
                                              offsets, ssrc, out, N);
}

// Round 3
// 488.866 us; speedup vs baseline: 1.9592x; 1.1406x over previous
//
#include <hip/hip_runtime.h>
#include <math.h>

#define FEAT 120
#define HCNT 4

__device__ __forceinline__ float nact_scale(float sumsq) {
    float n = sqrtf(sumsq + 1e-10f);
    float sig = 1.0f / (1.0f + expf(-n));
    return sig / n;
}

#define INV_S32 0.17677669529663687f   // 1/sqrt(32)
#define INV_S16 0.25f                  // 1/sqrt(16)
#define INV_S8  0.35355339059327373f   // 1/sqrt(8)
// tp_dot scales: 1/(sqrt(2l+1)*sqrt(fan)), fan = 32*32 + 16*16*3 + 8*8*5 = 2112
#define S_IR0 0.02175970668223486f
#define S_IR1 0.012562972567021898f
#define S_IR2 0.009731317442393031f

// ---------------- counting sort by dst ----------------

__global__ __launch_bounds__(256) void zero_int_kernel(int* __restrict__ p, int n) {
    int i = blockIdx.x * 256 + threadIdx.x;
    if (i < n) p[i] = 0;
}

__global__ __launch_bounds__(256) void hist_kernel(const int* __restrict__ dst,
                                                   int* __restrict__ cnt, int E) {
    int e = blockIdx.x * 256 + threadIdx.x;
    if (e < E) atomicAdd(&cnt[dst[e]], 1);
}

__global__ __launch_bounds__(256) void scan_block_kernel(const int* __restrict__ cnt,
                                                         int* __restrict__ excl,
                                                         int* __restrict__ bsum, int n) {
    __shared__ int s[256];
    int t = threadIdx.x;
    int i = blockIdx.x * 256 + t;
    int v = (i < n) ? cnt[i] : 0;
    s[t] = v;
    __syncthreads();
    for (int off = 1; off < 256; off <<= 1) {
        int add = (t >= off) ? s[t - off] : 0;
        __syncthreads();
        s[t] += add;
        __syncthreads();
    }
    if (i < n) excl[i] = s[t] - v;
    if (t == 255) bsum[blockIdx.x] = s[255];
}

__global__ __launch_bounds__(256) void scan_sums_kernel(int* __restrict__ bsum, int nb) {
    __shared__ int s[256];
    int t = threadIdx.x;
    int v = (t < nb) ? bsum[t] : 0;
    s[t] = v;
    __syncthreads();
    for (int off = 1; off < 256; off <<= 1) {
        int add = (t >= off) ? s[t - off] : 0;
        __syncthreads();
        s[t] += add;
        __syncthreads();
    }
    if (t < nb) bsum[t] = s[t] - v;
}

__global__ __launch_bounds__(256) void add_offsets_kernel(int* __restrict__ offsets,
                                                          const int* __restrict__ bsum,
                                                          int* __restrict__ cursor,
                                                          int n, int E) {
    int i = blockIdx.x * 256 + threadIdx.x;
    if (i < n) {
        int off = offsets[i] + bsum[i >> 8];
        offsets[i] = off;
        cursor[i] = off;
    }
    if (i == 0) offsets[n] = E;
}

__global__ __launch_bounds__(256) void scatter_kernel(const int* __restrict__ dst,
                                                      const int* __restrict__ src,
                                                      int* __restrict__ cursor,
                                                      int* __restrict__ ssrc, int E) {
    int e = blockIdx.x * 256 + threadIdx.x;
    if (e < E) {
        int pos = atomicAdd(&cursor[dst[e]], 1);
        ssrc[pos] = src[e];
    }
}

// ---- node kernel: q,k,v = norm_act(o3_linear(x)); tq = q x Wd (persistent grid) ----

__global__ __launch_bounds__(256) void node_kernel(
    const float* __restrict__ x,
    const float* __restrict__ Wq0, const float* __restrict__ Wq1, const float* __restrict__ Wq2,
    const float* __restrict__ Wk0, const float* __restrict__ Wk1, const float* __restrict__ Wk2,
    const float* __restrict__ Wv0, const float* __restrict__ Wv1, const float* __restrict__ Wv2,
    const float* __restrict__ Wd0, const float* __restrict__ Wd1, const float* __restrict__ Wd2,
    float* __restrict__ knode, float* __restrict__ vnode, float* __restrict__ tq, int N)
{
    __shared__ float sWq0[1024], sWq1[256], sWq2[64];
    __shared__ float sWk0[1024], sWk1[256], sWk2[64];
    __shared__ float sWv0[1024], sWv1[256], sWv2[64];
    __shared__ float4 sWd0[1024];
    __shared__ float4 sWd1[256];
    __shared__ float4 sWd2[64];
    __shared__ float qs[4][FEAT];

    int t = threadIdx.x;
    for (int i = t; i < 1024; i += 256) {
        sWq0[i] = Wq0[i]; sWk0[i] = Wk0[i]; sWv0[i] = Wv0[i];
        sWd0[i] = ((const float4*)Wd0)[i];
    }
    if (t < 256) { sWq1[t] = Wq1[t]; sWk1[t] = Wk1[t]; sWv1[t] = Wv1[t];
                   sWd1[t] = ((const float4*)Wd1)[t]; }
    if (t < 64)  { sWq2[t] = Wq2[t]; sWk2[t] = Wk2[t]; sWv2[t] = Wv2[t];
                   sWd2[t] = ((const float4*)Wd2)[t]; }
    __syncthreads();

    int lane = t & 63, wid = t >> 6;
    int ngrp = (N + 3) >> 2;
    for (int grp = blockIdx.x; grp < ngrp; grp += gridDim.x) {
        int node = grp * 4 + wid;
        bool active = node < N;
        if (active) {
            const float* xr = x + (size_t)node * FEAT;
            float* kr = knode + (size_t)node * FEAT;
            float* vr = vnode + (size_t)node * FEAT;
            if (lane < 32) {
                int o = lane;
                float q = 0, k = 0, v = 0;
                #pragma unroll 8
                for (int i = 0; i < 32; i++) {
                    float xi = xr[i];
                    q = fmaf(xi, sWq0[i * 32 + o], q);
                    k = fmaf(xi, sWk0[i * 32 + o], k);
                    v = fmaf(xi, sWv0[i * 32 + o], v);
                }
                q *= INV_S32; k *= INV_S32; v *= INV_S32;
                q *= nact_scale(q * q);
                k *= nact_scale(k * k);
                v *= nact_scale(v * v);
                kr[o] = k; vr[o] = v; qs[wid][o] = q;
            } else if (lane < 48) {
                int o = lane - 32;
                float q[3] = {0,0,0}, k[3] = {0,0,0}, v[3] = {0,0,0};
                for (int i = 0; i < 16; i++) {
                    float wq = sWq1[i * 16 + o], wk = sWk1[i * 16 + o], wv = sWv1[i * 16 + o];
                    #pragma unroll
                    for (int c = 0; c < 3; c++) {
                        float xi = xr[32 + i * 3 + c];
                        q[c] = fmaf(xi, wq, q[c]);
                        k[c] = fmaf(xi, wk, k[c]);
                        v[c] = fmaf(xi, wv, v[c]);
                    }
                }
                float nq = 0, nk = 0, nv = 0;
                #pragma unroll
                for (int c = 0; c < 3; c++) {
                    q[c] *= INV_S16; k[c] *= INV_S16; v[c] *= INV_S16;
                    nq += q[c]*q[c]; nk += k[c]*k[c]; nv += v[c]*v[c];
                }
                float sq = nact_scale(nq), sk = nact_scale(nk), sv = nact_scale(nv);
                #pragma unroll
                for (int c = 0; c < 3; c++) {
                    int f = 32 + o * 3 + c;
                    qs[wid][f] = q[c]*sq; kr[f] = k[c]*sk; vr[f] = v[c]*sv;
                }
            } else if (lane < 56) {
                int o = lane - 48;
                float q[5] = {0,0,0,0,0}, k[5] = {0,0,0,0,0}, v[5] = {0,0,0,0,0};
                for (int i = 0; i < 8; i++) {
                    float wq = sWq2[i * 8 + o], wk = sWk2[i * 8 + o], wv = sWv2[i * 8 + o];
                    #pragma unroll
                    for (int c = 0; c < 5; c++) {
                        float xi = xr[80 + i * 5 + c];
                        q[c] = fmaf(xi, wq, q[c]);
                        k[c] = fmaf(xi, wk, k[c]);
                        v[c] = fmaf(xi, wv, v[c]);
                    }
                }
                float nq = 0, nk = 0, nv = 0;
                #pragma unroll
                for (int c = 0; c < 5; c++) {
                    q[c] *= INV_S8; k[c] *= INV_S8; v[c] *= INV_S8;
                    nq += q[c]*q[c]; nk += k[c]*k[c]; nv += v[c]*v[c];
                }
                float sq = nact_scale(nq), sk = nact_scale(nk), sv = nact_scale(nv);
                #pragma unroll
                for (int c = 0; c < 5; c++) {
                    int f = 80 + o * 5 + c;
                    qs[wid][f] = q[c]*sq; kr[f] = k[c]*sk; vr[f] = v[c]*sv;
                }
            }
        }
        __syncthreads();
        if (active) {
            float* tr = tq + (size_t)node * (HCNT * FEAT);
            if (lane < 32) {
                int j = lane;
                float a0 = 0, a1 = 0, a2 = 0, a3 = 0;
                #pragma unroll 8
                for (int i = 0; i < 32; i++) {
                    float qi = qs[wid][i];
                    float4 w = sWd0[i * 32 + j];
                    a0 = fmaf(qi, w.x, a0); a1 = fmaf(qi, w.y, a1);
                    a2 = fmaf(qi, w.z, a2); a3 = fmaf(qi, w.w, a3);
                }
                tr[0 * FEAT + j] = a0 * S_IR0;
                tr[1 * FEAT + j] = a1 * S_IR0;
                tr[2 * FEAT + j] = a2 * S_IR0;
                tr[3 * FEAT + j] = a3 * S_IR0;
            } else if (lane < 48) {
                int j = lane - 32;
                float a[4][3] = {};
                for (int i = 0; i < 16; i++) {
                    float4 w = sWd1[i * 16 + j];
                    #pragma unroll
                    for (int c = 0; c < 3; c++) {
                        float qi = qs[wid][32 + i * 3 + c];
                        a[0][c] = fmaf(qi, w.x, a[0][c]);
                        a[1][c] = fmaf(qi, w.y, a[1][c]);
                        a[2][c] = fmaf(qi, w.z, a[2][c]);
                        a[3][c] = fmaf(qi, w.w, a[3][c]);
                    }
                }
                #pragma unroll
                for (int h = 0; h < 4; h++)
                    #pragma unroll
                    for (int c = 0; c < 3; c++)
                        tr[h * FEAT + 32 + j * 3 + c] = a[h][c] * S_IR1;
            } else if (lane < 56) {
                int j = lane - 48;
                float a[4][5] = {};
                for (int i = 0; i < 8; i++) {
                    float4 w = sWd2[i * 8 + j];
                    #pragma unroll
                    for (int c = 0; c < 5; c++) {
                        float qi = qs[wid][80 + i * 5 + c];
                        a[0][c] = fmaf(qi, w.x, a[0][c]);
                        a[1][c] = fmaf(qi, w.y, a[1][c]);
                        a[2][c] = fmaf(qi, w.z, a[2][c]);
                        a[3][c] = fmaf(qi, w.w, a[3][c]);
                    }
                }
                #pragma unroll
                for (int h = 0; h < 4; h++)
                    #pragma unroll
                    for (int c = 0; c < 5; c++)
                        tr[h * FEAT + 80 + j * 5 + c] = a[h][c] * S_IR2;
            }
        }
        __syncthreads();
    }
}

// ---------------- fused per-dst edge kernel (no LDS) ----------------

// head-packed wave reduction: 14 shuffles, 1 expf/lane.
// returns mean_h exp(dot_h) broadcast to all 64 lanes.
__device__ __forceinline__ float head_reduce(const float tA[4], const float tB[4],
                                             float k0, float k1, int lane) {
    float d0 = fmaf(tA[0], k0, tB[0] * k1);
    float d1 = fmaf(tA[1], k0, tB[1] * k1);
    float d2 = fmaf(tA[2], k0, tB[2] * k1);
    float d3 = fmaf(tA[3], k0, tB[3] * k1);
    // phase 1: fold to 16 residues (value now depends only on lane&15)
    d0 += __shfl_xor(d0, 16, 64); d0 += __shfl_xor(d0, 32, 64);
    d1 += __shfl_xor(d1, 16, 64); d1 += __shfl_xor(d1, 32, 64);
    d2 += __shfl_xor(d2, 16, 64); d2 += __shfl_xor(d2, 32, 64);
    d3 += __shfl_xor(d3, 16, 64); d3 += __shfl_xor(d3, 32, 64);
    // phase 2: group g=lane>>4 owns head g; fold its 16 residues
    int g = lane >> 4;
    float v = (g == 0) ? d0 : (g == 1) ? d1 : (g == 2) ? d2 : d3;
    v += __shfl_xor(v, 1, 64); v += __shfl_xor(v, 2, 64);
    v += __shfl_xor(v, 4, 64); v += __shfl_xor(v, 8, 64);
    // one exp per lane; sum the 4 head groups
    float e = expf(v);
    e += __shfl_xor(e, 16, 64);
    e += __shfl_xor(e, 32, 64);
    return 0.25f * e;
}

__global__ __launch_bounds__(256) void edge_fused_kernel(
    const float* __restrict__ tq, const float* __restrict__ knode,
    const float* __restrict__ vnode,
    const int* __restrict__ offsets, const int* __restrict__ ssrc,
    float* __restrict__ out, int N)
{
    int lane = threadIdx.x & 63, wid = threadIdx.x >> 6;
    int node = blockIdx.x * 4 + wid;
    if (node >= N) return;
    bool hi = lane < (FEAT - 64);

    const float* tr = tq + (size_t)node * (HCNT * FEAT);
    float tA[4], tB[4];
    #pragma unroll
    for (int h = 0; h < 4; h++) {
        tA[h] = tr[h * FEAT + lane];
        tB[h] = hi ? tr[h * FEAT + 64 + lane] : 0.0f;
    }

    int beg = offsets[node], end = offsets[node + 1];
    float zsum = 0.0f, acc0 = 0.0f, acc1 = 0.0f;

    int p = beg;
    for (; p + 2 <= end; p += 2) {
        int s0 = __builtin_amdgcn_readfirstlane(ssrc[p]);
        int s1 = __builtin_amdgcn_readfirstlane(ssrc[p + 1]);
        const float* kr0 = knode + (size_t)s0 * FEAT;
        const float* kr1 = knode + (size_t)s1 * FEAT;
        const float* vr0 = vnode + (size_t)s0 * FEAT;
        const float* vr1 = vnode + (size_t)s1 * FEAT;
        float k0a = kr0[lane], k1a = hi ? kr0[64 + lane] : 0.0f;
        float k0b = kr1[lane], k1b = hi ? kr1[64 + lane] : 0.0f;
        float v0a = vr0[lane], v1a = hi ? vr0[64 + lane] : 0.0f;
        float v0b = vr1[lane], v1b = hi ? vr1[64 + lane] : 0.0f;
        float exa = head_reduce(tA, tB, k0a, k1a, lane);
        float exb = head_reduce(tA, tB, k0b, k1b, lane);
        zsum += exa + exb;
        float wa = sqrtf(exa), wb = sqrtf(exb);
        acc0 = fmaf(wa, v0a, acc0); acc1 = fmaf(wa, v1a, acc1);
        acc0 = fmaf(wb, v0b, acc0); acc1 = fmaf(wb, v1b, acc1);
    }
    if (p < end) {
        int s0 = __builtin_amdgcn_readfirstlane(ssrc[p]);
        const float* kr0 = knode + (size_t)s0 * FEAT;
        const float* vr0 = vnode + (size_t)s0 * FEAT;
        float k0a = kr0[lane], k1a = hi ? kr0[64 + lane] : 0.0f;
        float v0a = vr0[lane], v1a = hi ? vr0[64 + lane] : 0.0f;
        float exa = head_reduce(tA, tB, k0a, k1a, lane);
        zsum += exa;
        float wa = sqrtf(exa);
        acc0 = fmaf(wa, v0a, acc0); acc1 = fmaf(wa, v1a, acc1);
    }

    float scale = (zsum > 0.0f) ? rsqrtf(zsum) : 0.0f;
    const float* vself = vnode + (size_t)node * FEAT;
    float* orow = out + (size_t)node * FEAT;
    orow[lane] = vself[lane] + acc0 * scale;
    if (hi) orow[64 + lane] = vself[64 + lane] + acc1 * scale;
}

// ---------------- launch ----------------

extern "C" void kernel_launch(void* const* d_in, const int* in_sizes, int n_in,
                              void* d_out, int out_size, void* d_ws, size_t ws_size,
                              hipStream_t stream) {
    const float* x   = (const float*)d_in[0];
    const float* Wq0 = (const float*)d_in[1];
    const float* Wq1 = (const float*)d_in[2];
    const float* Wq2 = (const float*)d_in[3];
    const float* Wk0 = (const float*)d_in[4];
    const float* Wk1 = (const float*)d_in[5];
    const float* Wk2 = (const float*)d_in[6];
    const float* Wv0 = (const float*)d_in[7];
    const float* Wv1 = (const float*)d_in[8];
    const float* Wv2 = (const float*)d_in[9];
    const float* Wd0 = (const float*)d_in[10];
    const float* Wd1 = (const float*)d_in[11];
    const float* Wd2 = (const float*)d_in[12];
    const int* edge_dst = (const int*)d_in[13];
    const int* edge_src = (const int*)d_in[14];
    float* out = (float*)d_out;

    int N = in_sizes[0] / FEAT;
    int E = in_sizes[13];

    float* ws = (float*)d_ws;
    float* knode = ws;                                  // N*120
    float* vnode = knode + (size_t)N * FEAT;            // N*120
    float* tq    = vnode + (size_t)N * FEAT;            // N*480
    int* offsets = (int*)(tq + (size_t)N * HCNT * FEAT);// N+1
    int* cursor  = offsets + (N + 1);                   // N
    int* bsum    = cursor + N;                          // 256
    int* ssrc    = bsum + 256;                          // E

    int NB = (N + 255) / 256;      // 196
    int EB = (E + 255) / 256;      // 3125
    int NW = (N + 3) / 4;          // 12500

    zero_int_kernel<<<NB, 256, 0, stream>>>(cursor, N);
    hist_kernel<<<EB, 256, 0, stream>>>(edge_dst, cursor, E);
    scan_block_kernel<<<NB, 256, 0, stream>>>(cursor, offsets, bsum, N);
    scan_sums_kernel<<<1, 256, 0, stream>>>(bsum, NB);
    add_offsets_kernel<<<NB, 256, 0, stream>>>(offsets, bsum, cursor, N, E);
    scatter_kernel<<<EB, 256, 0, stream>>>(edge_dst, edge_src, cursor, ssrc, E);

    node_kernel<<<1024, 256, 0, stream>>>(x, Wq0, Wq1, Wq2, Wk0, Wk1, Wk2,
                                          Wv0, Wv1, Wv2, Wd0, Wd1, Wd2,
                                          knode, vnode, tq, N);
    edge_fused_kernel<<<NW, 256, 0, stream>>>(tq, knode, vnode, offsets, ssrc, out, N);
}

// Round 4
// 458.221 us; speedup vs baseline: 2.0902x; 1.0669x over previous
//
#include <hip/hip_runtime.h>
#include <math.h>

#define FEAT 120
#define HCNT 4

__device__ __forceinline__ float nact_scale(float sumsq) {
    float n = sqrtf(sumsq + 1e-10f);
    float sig = 1.0f / (1.0f + expf(-n));
    return sig / n;
}

#define INV_S32 0.17677669529663687f   // 1/sqrt(32)
#define INV_S16 0.25f                  // 1/sqrt(16)
#define INV_S8  0.35355339059327373f   // 1/sqrt(8)
// tp_dot scales: 1/(sqrt(2l+1)*sqrt(fan)), fan = 32*32 + 16*16*3 + 8*8*5 = 2112
#define S_IR0 0.02175970668223486f
#define S_IR1 0.012562972567021898f
#define S_IR2 0.009731317442393031f

// ---------------- counting sort by dst ----------------

__global__ __launch_bounds__(256) void zero_int_kernel(int* __restrict__ p, int n) {
    int i = blockIdx.x * 256 + threadIdx.x;
    if (i < n) p[i] = 0;
}

__global__ __launch_bounds__(256) void hist_kernel(const int* __restrict__ dst,
                                                   int* __restrict__ cnt, int E) {
    int e = blockIdx.x * 256 + threadIdx.x;
    if (e < E) atomicAdd(&cnt[dst[e]], 1);
}

__global__ __launch_bounds__(256) void scan_block_kernel(const int* __restrict__ cnt,
                                                         int* __restrict__ excl,
                                                         int* __restrict__ bsum, int n) {
    __shared__ int s[256];
    int t = threadIdx.x;
    int i = blockIdx.x * 256 + t;
    int v = (i < n) ? cnt[i] : 0;
    s[t] = v;
    __syncthreads();
    for (int off = 1; off < 256; off <<= 1) {
        int add = (t >= off) ? s[t - off] : 0;
        __syncthreads();
        s[t] += add;
        __syncthreads();
    }
    if (i < n) excl[i] = s[t] - v;
    if (t == 255) bsum[blockIdx.x] = s[255];
}

__global__ __launch_bounds__(256) void scan_sums_kernel(int* __restrict__ bsum, int nb) {
    __shared__ int s[256];
    int t = threadIdx.x;
    int v = (t < nb) ? bsum[t] : 0;
    s[t] = v;
    __syncthreads();
    for (int off = 1; off < 256; off <<= 1) {
        int add = (t >= off) ? s[t - off] : 0;
        __syncthreads();
        s[t] += add;
        __syncthreads();
    }
    if (t < nb) bsum[t] = s[t] - v;
}

__global__ __launch_bounds__(256) void add_offsets_kernel(int* __restrict__ offsets,
                                                          const int* __restrict__ bsum,
                                                          int* __restrict__ cursor,
                                                          int n, int E) {
    int i = blockIdx.x * 256 + threadIdx.x;
    if (i < n) {
        int off = offsets[i] + bsum[i >> 8];
        offsets[i] = off;
        cursor[i] = off;
    }
    if (i == 0) offsets[n] = E;
}

__global__ __launch_bounds__(256) void scatter_kernel(const int* __restrict__ dst,
                                                      const int* __restrict__ src,
                                                      int* __restrict__ cursor,
                                                      int* __restrict__ ssrc, int E) {
    int e = blockIdx.x * 256 + threadIdx.x;
    if (e < E) {
        int pos = atomicAdd(&cursor[dst[e]], 1);
        ssrc[pos] = src[e];
    }
}

// ---- node_qkv: q,k,v = norm_act(o3_linear(x)) — 16 KB LDS, no in-loop barriers ----

__global__ __launch_bounds__(256) void node_qkv_kernel(
    const float* __restrict__ x,
    const float* __restrict__ Wq0, const float* __restrict__ Wq1, const float* __restrict__ Wq2,
    const float* __restrict__ Wk0, const float* __restrict__ Wk1, const float* __restrict__ Wk2,
    const float* __restrict__ Wv0, const float* __restrict__ Wv1, const float* __restrict__ Wv2,
    float* __restrict__ qnode, float* __restrict__ knode, float* __restrict__ vnode, int N)
{
    __shared__ float sWq0[1024], sWq1[256], sWq2[64];
    __shared__ float sWk0[1024], sWk1[256], sWk2[64];
    __shared__ float sWv0[1024], sWv1[256], sWv2[64];

    int t = threadIdx.x;
    for (int i = t; i < 1024; i += 256) { sWq0[i] = Wq0[i]; sWk0[i] = Wk0[i]; sWv0[i] = Wv0[i]; }
    if (t < 256) { sWq1[t] = Wq1[t]; sWk1[t] = Wk1[t]; sWv1[t] = Wv1[t]; }
    if (t < 64)  { sWq2[t] = Wq2[t]; sWk2[t] = Wk2[t]; sWv2[t] = Wv2[t]; }
    __syncthreads();

    int lane = t & 63, wid = t >> 6;
    int ngrp = (N + 3) >> 2;
    for (int grp = blockIdx.x; grp < ngrp; grp += gridDim.x) {
        int node = __builtin_amdgcn_readfirstlane(grp * 4 + wid);
        if (node >= N) continue;
        const float* xr = x + (size_t)node * FEAT;
        float* qr = qnode + (size_t)node * FEAT;
        float* kr = knode + (size_t)node * FEAT;
        float* vr = vnode + (size_t)node * FEAT;
        if (lane < 32) {
            int o = lane;
            float q = 0, k = 0, v = 0;
            #pragma unroll 8
            for (int i = 0; i < 32; i++) {
                float xi = xr[i];
                q = fmaf(xi, sWq0[i * 32 + o], q);
                k = fmaf(xi, sWk0[i * 32 + o], k);
                v = fmaf(xi, sWv0[i * 32 + o], v);
            }
            q *= INV_S32; k *= INV_S32; v *= INV_S32;
            q *= nact_scale(q * q);
            k *= nact_scale(k * k);
            v *= nact_scale(v * v);
            qr[o] = q; kr[o] = k; vr[o] = v;
        } else if (lane < 48) {
            int o = lane - 32;
            float q[3] = {0,0,0}, k[3] = {0,0,0}, v[3] = {0,0,0};
            for (int i = 0; i < 16; i++) {
                float wq = sWq1[i * 16 + o], wk = sWk1[i * 16 + o], wv = sWv1[i * 16 + o];
                #pragma unroll
                for (int c = 0; c < 3; c++) {
                    float xi = xr[32 + i * 3 + c];
                    q[c] = fmaf(xi, wq, q[c]);
                    k[c] = fmaf(xi, wk, k[c]);
                    v[c] = fmaf(xi, wv, v[c]);
                }
            }
            float nq = 0, nk = 0, nv = 0;
            #pragma unroll
            for (int c = 0; c < 3; c++) {
                q[c] *= INV_S16; k[c] *= INV_S16; v[c] *= INV_S16;
                nq += q[c]*q[c]; nk += k[c]*k[c]; nv += v[c]*v[c];
            }
            float sq = nact_scale(nq), sk = nact_scale(nk), sv = nact_scale(nv);
            #pragma unroll
            for (int c = 0; c < 3; c++) {
                int f = 32 + o * 3 + c;
                qr[f] = q[c]*sq; kr[f] = k[c]*sk; vr[f] = v[c]*sv;
            }
        } else if (lane < 56) {
            int o = lane - 48;
            float q[5] = {0,0,0,0,0}, k[5] = {0,0,0,0,0}, v[5] = {0,0,0,0,0};
            for (int i = 0; i < 8; i++) {
                float wq = sWq2[i * 8 + o], wk = sWk2[i * 8 + o], wv = sWv2[i * 8 + o];
                #pragma unroll
                for (int c = 0; c < 5; c++) {
                    float xi = xr[80 + i * 5 + c];
                    q[c] = fmaf(xi, wq, q[c]);
                    k[c] = fmaf(xi, wk, k[c]);
                    v[c] = fmaf(xi, wv, v[c]);
                }
            }
            float nq = 0, nk = 0, nv = 0;
            #pragma unroll
            for (int c = 0; c < 5; c++) {
                q[c] *= INV_S8; k[c] *= INV_S8; v[c] *= INV_S8;
                nq += q[c]*q[c]; nk += k[c]*k[c]; nv += v[c]*v[c];
            }
            float sq = nact_scale(nq), sk = nact_scale(nk), sv = nact_scale(nv);
            #pragma unroll
            for (int c = 0; c < 5; c++) {
                int f = 80 + o * 5 + c;
                qr[f] = q[c]*sq; kr[f] = k[c]*sk; vr[f] = v[c]*sv;
            }
        }
    }
}

// ---- node_tq: tq[n][h][f] = sum_i q[i]*Wd[i,j,h]*scale — 23.4 KB LDS ----

__global__ __launch_bounds__(256) void node_tq_kernel(
    const float* __restrict__ qnode,
    const float* __restrict__ Wd0, const float* __restrict__ Wd1, const float* __restrict__ Wd2,
    float* __restrict__ tq, int N)
{
    __shared__ float4 sWd0[1024];
    __shared__ float4 sWd1[256];
    __shared__ float4 sWd2[64];
    __shared__ float qs[4][FEAT];

    int t = threadIdx.x;
    for (int i = t; i < 1024; i += 256) sWd0[i] = ((const float4*)Wd0)[i];
    if (t < 256) sWd1[t] = ((const float4*)Wd1)[t];
    if (t < 64)  sWd2[t] = ((const float4*)Wd2)[t];
    __syncthreads();

    int lane = t & 63, wid = t >> 6;
    int ngrp = (N + 3) >> 2;
    for (int grp = blockIdx.x; grp < ngrp; grp += gridDim.x) {
        int node = __builtin_amdgcn_readfirstlane(grp * 4 + wid);
        if (node >= N) continue;
        const float* qr = qnode + (size_t)node * FEAT;
        // wave-cooperative stage of q row into per-wave LDS (wave-private buffer)
        qs[wid][lane] = qr[lane];
        if (lane < FEAT - 64) qs[wid][64 + lane] = qr[64 + lane];
        __builtin_amdgcn_wave_barrier();

        float* tr = tq + (size_t)node * (HCNT * FEAT);
        if (lane < 32) {
            int j = lane;
            float a0 = 0, a1 = 0, a2 = 0, a3 = 0;
            #pragma unroll 8
            for (int i = 0; i < 32; i++) {
                float qi = qs[wid][i];
                float4 w = sWd0[i * 32 + j];
                a0 = fmaf(qi, w.x, a0); a1 = fmaf(qi, w.y, a1);
                a2 = fmaf(qi, w.z, a2); a3 = fmaf(qi, w.w, a3);
            }
            tr[0 * FEAT + j] = a0 * S_IR0;
            tr[1 * FEAT + j] = a1 * S_IR0;
            tr[2 * FEAT + j] = a2 * S_IR0;
            tr[3 * FEAT + j] = a3 * S_IR0;
        } else if (lane < 48) {
            int j = lane - 32;
            float a[4][3] = {};
            for (int i = 0; i < 16; i++) {
                float4 w = sWd1[i * 16 + j];
                #pragma unroll
                for (int c = 0; c < 3; c++) {
                    float qi = qs[wid][32 + i * 3 + c];
                    a[0][c] = fmaf(qi, w.x, a[0][c]);
                    a[1][c] = fmaf(qi, w.y, a[1][c]);
                    a[2][c] = fmaf(qi, w.z, a[2][c]);
                    a[3][c] = fmaf(qi, w.w, a[3][c]);
                }
            }
            #pragma unroll
            for (int h = 0; h < 4; h++)
                #pragma unroll
                for (int c = 0; c < 3; c++)
                    tr[h * FEAT + 32 + j * 3 + c] = a[h][c] * S_IR1;
        } else if (lane < 56) {
            int j = lane - 48;
            float a[4][5] = {};
            for (int i = 0; i < 8; i++) {
                float4 w = sWd2[i * 8 + j];
                #pragma unroll
                for (int c = 0; c < 5; c++) {
                    float qi = qs[wid][80 + i * 5 + c];
                    a[0][c] = fmaf(qi, w.x, a[0][c]);
                    a[1][c] = fmaf(qi, w.y, a[1][c]);
                    a[2][c] = fmaf(qi, w.z, a[2][c]);
                    a[3][c] = fmaf(qi, w.w, a[3][c]);
                }
            }
            #pragma unroll
            for (int h = 0; h < 4; h++)
                #pragma unroll
                for (int c = 0; c < 5; c++)
                    tr[h * FEAT + 80 + j * 5 + c] = a[h][c] * S_IR2;
        }
        __builtin_amdgcn_wave_barrier();  // qs reuse next iter: keep ordering
    }
}

// ---------------- fused per-dst edge kernel (no LDS) ----------------

// head-packed wave reduction: 14 shuffles, 1 expf/lane.
__device__ __forceinline__ float head_reduce(const float tA[4], const float tB[4],
                                             float k0, float k1, int lane) {
    float d0 = fmaf(tA[0], k0, tB[0] * k1);
    float d1 = fmaf(tA[1], k0, tB[1] * k1);
    float d2 = fmaf(tA[2], k0, tB[2] * k1);
    float d3 = fmaf(tA[3], k0, tB[3] * k1);
    d0 += __shfl_xor(d0, 16, 64); d0 += __shfl_xor(d0, 32, 64);
    d1 += __shfl_xor(d1, 16, 64); d1 += __shfl_xor(d1, 32, 64);
    d2 += __shfl_xor(d2, 16, 64); d2 += __shfl_xor(d2, 32, 64);
    d3 += __shfl_xor(d3, 16, 64); d3 += __shfl_xor(d3, 32, 64);
    int g = lane >> 4;
    float v = (g == 0) ? d0 : (g == 1) ? d1 : (g == 2) ? d2 : d3;
    v += __shfl_xor(v, 1, 64); v += __shfl_xor(v, 2, 64);
    v += __shfl_xor(v, 4, 64); v += __shfl_xor(v, 8, 64);
    float e = expf(v);
    e += __shfl_xor(e, 16, 64);
    e += __shfl_xor(e, 32, 64);
    return 0.25f * e;
}

__global__ __launch_bounds__(256) void edge_fused_kernel(
    const float* __restrict__ tq, const float* __restrict__ knode,
    const float* __restrict__ vnode,
    const int* __restrict__ offsets, const int* __restrict__ ssrc,
    float* __restrict__ out, int N)
{
    int lane = threadIdx.x & 63, wid = threadIdx.x >> 6;
    int node = blockIdx.x * 4 + wid;
    if (node >= N) return;
    node = __builtin_amdgcn_readfirstlane(node);
    bool hi = lane < (FEAT - 64);

    const float* tr = tq + (size_t)node * (HCNT * FEAT);
    float tA[4], tB[4];
    #pragma unroll
    for (int h = 0; h < 4; h++) {
        tA[h] = tr[h * FEAT + lane];
        tB[h] = hi ? tr[h * FEAT + 64 + lane] : 0.0f;
    }

    int beg = offsets[node], end = offsets[node + 1];
    float zsum = 0.0f, acc0 = 0.0f, acc1 = 0.0f;

    int p = beg;
    for (; p + 4 <= end; p += 4) {
        int s0 = __builtin_amdgcn_readfirstlane(ssrc[p]);
        int s1 = __builtin_amdgcn_readfirstlane(ssrc[p + 1]);
        int s2 = __builtin_amdgcn_readfirstlane(ssrc[p + 2]);
        int s3 = __builtin_amdgcn_readfirstlane(ssrc[p + 3]);
        const float* kr0 = knode + (size_t)s0 * FEAT;
        const float* kr1 = knode + (size_t)s1 * FEAT;
        const float* kr2 = knode + (size_t)s2 * FEAT;
        const float* kr3 = knode + (size_t)s3 * FEAT;
        const float* vr0 = vnode + (size_t)s0 * FEAT;
        const float* vr1 = vnode + (size_t)s1 * FEAT;
        const float* vr2 = vnode + (size_t)s2 * FEAT;
        const float* vr3 = vnode + (size_t)s3 * FEAT;
        float k0a = kr0[lane], k1a = hi ? kr0[64 + lane] : 0.0f;
        float k0b = kr1[lane], k1b = hi ? kr1[64 + lane] : 0.0f;
        float k0c = kr2[lane], k1c = hi ? kr2[64 + lane] : 0.0f;
        float k0d = kr3[lane], k1d = hi ? kr3[64 + lane] : 0.0f;
        float v0a = vr0[lane], v1a = hi ? vr0[64 + lane] : 0.0f;
        float v0b = vr1[lane], v1b = hi ? vr1[64 + lane] : 0.0f;
        float v0c = vr2[lane], v1c = hi ? vr2[64 + lane] : 0.0f;
        float v0d = vr3[lane], v1d = hi ? vr3[64 + lane] : 0.0f;
        float exa = head_reduce(tA, tB, k0a, k1a, lane);
        float exb = head_reduce(tA, tB, k0b, k1b, lane);
        float exc = head_reduce(tA, tB, k0c, k1c, lane);
        float exd = head_reduce(tA, tB, k0d, k1d, lane);
        zsum += (exa + exb) + (exc + exd);
        float wa = sqrtf(exa), wb = sqrtf(exb), wc = sqrtf(exc), wd = sqrtf(exd);
        acc0 = fmaf(wa, v0a, acc0); acc1 = fmaf(wa, v1a, acc1);
        acc0 = fmaf(wb, v0b, acc0); acc1 = fmaf(wb, v1b, acc1);
        acc0 = fmaf(wc, v0c, acc0); acc1 = fmaf(wc, v1c, acc1);
        acc0 = fmaf(wd, v0d, acc0); acc1 = fmaf(wd, v1d, acc1);
    }
    for (; p < end; ++p) {
        int s0 = __builtin_amdgcn_readfirstlane(ssrc[p]);
        const float* kr0 = knode + (size_t)s0 * FEAT;
        const float* vr0 = vnode + (size_t)s0 * FEAT;
        float k0a = kr0[lane], k1a = hi ? kr0[64 + lane] : 0.0f;
        float v0a = vr0[lane], v1a = hi ? vr0[64 + lane] : 0.0f;
        float exa = head_reduce(tA, tB, k0a, k1a, lane);
        zsum += exa;
        float wa = sqrtf(exa);
        acc0 = fmaf(wa, v0a, acc0); acc1 = fmaf(wa, v1a, acc1);
    }

    float scale = (zsum > 0.0f) ? rsqrtf(zsum) : 0.0f;
    const float* vself = vnode + (size_t)node * FEAT;
    float* orow = out + (size_t)node * FEAT;
    orow[lane] = vself[lane] + acc0 * scale;
    if (hi) orow[64 + lane] = vself[64 + lane] + acc1 * scale;
}

// ---------------- launch ----------------

extern "C" void kernel_launch(void* const* d_in, const int* in_sizes, int n_in,
                              void* d_out, int out_size, void* d_ws, size_t ws_size,
                              hipStream_t stream) {
    const float* x   = (const float*)d_in[0];
    const float* Wq0 = (const float*)d_in[1];
    const float* Wq1 = (const float*)d_in[2];
    const float* Wq2 = (const float*)d_in[3];
    const float* Wk0 = (const float*)d_in[4];
    const float* Wk1 = (const float*)d_in[5];
    const float* Wk2 = (const float*)d_in[6];
    const float* Wv0 = (const float*)d_in[7];
    const float* Wv1 = (const float*)d_in[8];
    const float* Wv2 = (const float*)d_in[9];
    const float* Wd0 = (const float*)d_in[10];
    const float* Wd1 = (const float*)d_in[11];
    const float* Wd2 = (const float*)d_in[12];
    const int* edge_dst = (const int*)d_in[13];
    const int* edge_src = (const int*)d_in[14];
    float* out = (float*)d_out;

    int N = in_sizes[0] / FEAT;
    int E = in_sizes[13];

    float* ws = (float*)d_ws;
    float* qnode = ws;                                  // N*120
    float* knode = qnode + (size_t)N * FEAT;            // N*120
    float* vnode = knode + (size_t)N * FEAT;            // N*120
    float* tq    = vnode + (size_t)N * FEAT;            // N*480
    int* offsets = (int*)(tq + (size_t)N * HCNT * FEAT);// N+1
    int* cursor  = offsets + (N + 1);                   // N
    int* bsum    = cursor + N;                          // 256
    int* ssrc    = bsum + 256;                          // E

    int NB = (N + 255) / 256;
    int EB = (E + 255) / 256;
    int NW = (N + 3) / 4;

    zero_int_kernel<<<NB, 256, 0, stream>>>(cursor, N);
    hist_kernel<<<EB, 256, 0, stream>>>(edge_dst, cursor, E);
    scan_block_kernel<<<NB, 256, 0, stream>>>(cursor, offsets, bsum, N);
    scan_sums_kernel<<<1, 256, 0, stream>>>(bsum, NB);
    add_offsets_kernel<<<NB, 256, 0, stream>>>(offsets, bsum, cursor, N, E);
    scatter_kernel<<<EB, 256, 0, stream>>>(edge_dst, edge_src, cursor, ssrc, E);

    node_qkv_kernel<<<2048, 256, 0, stream>>>(x, Wq0, Wq1, Wq2, Wk0, Wk1, Wk2,
                                              Wv0, Wv1, Wv2, qnode, knode, vnode, N);
    node_tq_kernel<<<2048, 256, 0, stream>>>(qnode, Wd0, Wd1, Wd2, tq, N);
    edge_fused_kernel<<<NW, 256, 0, stream>>>(tq, knode, vnode, offsets, ssrc, out, N);
}

// Round 5
// 398.734 us; speedup vs baseline: 2.4020x; 1.1492x over previous
//
#include <hip/hip_runtime.h>
#include <math.h>

#define FEAT 120
#define HCNT 4

typedef unsigned short ushort_t;
typedef unsigned int uint_t;
typedef __attribute__((ext_vector_type(8))) short short8;
typedef __attribute__((ext_vector_type(4))) float floatx4;

__device__ __forceinline__ float nact_scale(float sumsq) {
    float n = sqrtf(sumsq + 1e-10f);
    float sig = 1.0f / (1.0f + expf(-n));
    return sig / n;
}

__device__ __forceinline__ ushort_t bf16r(float f) {
    uint_t u = __float_as_uint(f);
    u += 0x7fff + ((u >> 16) & 1);   // round-to-nearest-even
    return (ushort_t)(u >> 16);
}

#define INV_S32 0.17677669529663687f   // 1/sqrt(32)
#define INV_S16 0.25f                  // 1/sqrt(16)
#define INV_S8  0.35355339059327373f   // 1/sqrt(8)
// tp_dot scales: 1/(sqrt(2l+1)*sqrt(fan)), fan = 32*32 + 16*16*3 + 8*8*5 = 2112
#define S_IR0 0.02175970668223486f
#define S_IR1 0.012562972567021898f
#define S_IR2 0.009731317442393031f

// ---------------- counting sort by dst ----------------

__global__ __launch_bounds__(256) void zero_int_kernel(int* __restrict__ p, int n) {
    int i = blockIdx.x * 256 + threadIdx.x;
    if (i < n) p[i] = 0;
}

__global__ __launch_bounds__(256) void hist_kernel(const int* __restrict__ dst,
                                                   int* __restrict__ cnt, int E) {
    int e = blockIdx.x * 256 + threadIdx.x;
    if (e < E) atomicAdd(&cnt[dst[e]], 1);
}

__global__ __launch_bounds__(256) void scan_block_kernel(const int* __restrict__ cnt,
                                                         int* __restrict__ excl,
                                                         int* __restrict__ bsum, int n) {
    __shared__ int s[256];
    int t = threadIdx.x;
    int i = blockIdx.x * 256 + t;
    int v = (i < n) ? cnt[i] : 0;
    s[t] = v;
    __syncthreads();
    for (int off = 1; off < 256; off <<= 1) {
        int add = (t >= off) ? s[t - off] : 0;
        __syncthreads();
        s[t] += add;
        __syncthreads();
    }
    if (i < n) excl[i] = s[t] - v;
    if (t == 255) bsum[blockIdx.x] = s[255];
}

__global__ __launch_bounds__(256) void scan_sums_kernel(int* __restrict__ bsum, int nb) {
    __shared__ int s[256];
    int t = threadIdx.x;
    int v = (t < nb) ? bsum[t] : 0;
    s[t] = v;
    __syncthreads();
    for (int off = 1; off < 256; off <<= 1) {
        int add = (t >= off) ? s[t - off] : 0;
        __syncthreads();
        s[t] += add;
        __syncthreads();
    }
    if (t < nb) bsum[t] = s[t] - v;
}

__global__ __launch_bounds__(256) void add_offsets_kernel(int* __restrict__ offsets,
                                                          const int* __restrict__ bsum,
                                                          int* __restrict__ cursor,
                                                          int n, int E) {
    int i = blockIdx.x * 256 + threadIdx.x;
    if (i < n) {
        int off = offsets[i] + bsum[i >> 8];
        offsets[i] = off;
        cursor[i] = off;
    }
    if (i == 0) offsets[n] = E;
}

__global__ __launch_bounds__(256) void scatter_kernel(const int* __restrict__ dst,
                                                      const int* __restrict__ src,
                                                      int* __restrict__ cursor,
                                                      int* __restrict__ ssrc, int E) {
    int e = blockIdx.x * 256 + threadIdx.x;
    if (e < E) {
        int pos = atomicAdd(&cursor[dst[e]], 1);
        ssrc[pos] = src[e];
    }
}

// ---- node_qkv: q,k,v = norm_act(o3_linear(x)); k,v -> bf16 padded rows; out=v ----

__global__ __launch_bounds__(256) void node_qkv_kernel(
    const float* __restrict__ x,
    const float* __restrict__ Wq0, const float* __restrict__ Wq1, const float* __restrict__ Wq2,
    const float* __restrict__ Wk0, const float* __restrict__ Wk1, const float* __restrict__ Wk2,
    const float* __restrict__ Wv0, const float* __restrict__ Wv1, const float* __restrict__ Wv2,
    float* __restrict__ qnode, ushort_t* __restrict__ kb, ushort_t* __restrict__ vb,
    float* __restrict__ out, int N)
{
    __shared__ float sWq0[1024], sWq1[256], sWq2[64];
    __shared__ float sWk0[1024], sWk1[256], sWk2[64];
    __shared__ float sWv0[1024], sWv1[256], sWv2[64];

    int t = threadIdx.x;
    for (int i = t; i < 1024; i += 256) { sWq0[i] = Wq0[i]; sWk0[i] = Wk0[i]; sWv0[i] = Wv0[i]; }
    if (t < 256) { sWq1[t] = Wq1[t]; sWk1[t] = Wk1[t]; sWv1[t] = Wv1[t]; }
    if (t < 64)  { sWq2[t] = Wq2[t]; sWk2[t] = Wk2[t]; sWv2[t] = Wv2[t]; }
    __syncthreads();

    int lane = t & 63, wid = t >> 6;
    int ngrp = (N + 3) >> 2;
    for (int grp = blockIdx.x; grp < ngrp; grp += gridDim.x) {
        int node = __builtin_amdgcn_readfirstlane(grp * 4 + wid);
        if (node >= N) continue;
        const float* xr = x + (size_t)node * FEAT;
        float* qr = qnode + (size_t)node * FEAT;
        ushort_t* kr = kb + (size_t)node * 128;
        ushort_t* vr = vb + (size_t)node * 128;
        float* orow = out + (size_t)node * FEAT;
        if (lane < 32) {
            int o = lane;
            float q = 0, k = 0, v = 0;
            #pragma unroll 8
            for (int i = 0; i < 32; i++) {
                float xi = xr[i];
                q = fmaf(xi, sWq0[i * 32 + o], q);
                k = fmaf(xi, sWk0[i * 32 + o], k);
                v = fmaf(xi, sWv0[i * 32 + o], v);
            }
            q *= INV_S32; k *= INV_S32; v *= INV_S32;
            q *= nact_scale(q * q);
            k *= nact_scale(k * k);
            v *= nact_scale(v * v);
            qr[o] = q; kr[o] = bf16r(k); vr[o] = bf16r(v); orow[o] = v;
        } else if (lane < 48) {
            int o = lane - 32;
            float q[3] = {0,0,0}, k[3] = {0,0,0}, v[3] = {0,0,0};
            for (int i = 0; i < 16; i++) {
                float wq = sWq1[i * 16 + o], wk = sWk1[i * 16 + o], wv = sWv1[i * 16 + o];
                #pragma unroll
                for (int c = 0; c < 3; c++) {
                    float xi = xr[32 + i * 3 + c];
                    q[c] = fmaf(xi, wq, q[c]);
                    k[c] = fmaf(xi, wk, k[c]);
                    v[c] = fmaf(xi, wv, v[c]);
                }
            }
            float nq = 0, nk = 0, nv = 0;
            #pragma unroll
            for (int c = 0; c < 3; c++) {
                q[c] *= INV_S16; k[c] *= INV_S16; v[c] *= INV_S16;
                nq += q[c]*q[c]; nk += k[c]*k[c]; nv += v[c]*v[c];
            }
            float sq = nact_scale(nq), sk = nact_scale(nk), sv = nact_scale(nv);
            #pragma unroll
            for (int c = 0; c < 3; c++) {
                int f = 32 + o * 3 + c;
                float vv = v[c]*sv;
                qr[f] = q[c]*sq; kr[f] = bf16r(k[c]*sk); vr[f] = bf16r(vv); orow[f] = vv;
            }
        } else if (lane < 56) {
            int o = lane - 48;
            float q[5] = {0,0,0,0,0}, k[5] = {0,0,0,0,0}, v[5] = {0,0,0,0,0};
            for (int i = 0; i < 8; i++) {
                float wq = sWq2[i * 8 + o], wk = sWk2[i * 8 + o], wv = sWv2[i * 8 + o];
                #pragma unroll
                for (int c = 0; c < 5; c++) {
                    float xi = xr[80 + i * 5 + c];
                    q[c] = fmaf(xi, wq, q[c]);
                    k[c] = fmaf(xi, wk, k[c]);
                    v[c] = fmaf(xi, wv, v[c]);
                }
            }
            float nq = 0, nk = 0, nv = 0;
            #pragma unroll
            for (int c = 0; c < 5; c++) {
                q[c] *= INV_S8; k[c] *= INV_S8; v[c] *= INV_S8;
                nq += q[c]*q[c]; nk += k[c]*k[c]; nv += v[c]*v[c];
            }
            float sq = nact_scale(nq), sk = nact_scale(nk), sv = nact_scale(nv);
            #pragma unroll
            for (int c = 0; c < 5; c++) {
                int f = 80 + o * 5 + c;
                float vv = v[c]*sv;
                qr[f] = q[c]*sq; kr[f] = bf16r(k[c]*sk); vr[f] = bf16r(vv); orow[f] = vv;
            }
        } else {
            // lanes 56..63: zero the bf16 row pads (features 120..127)
            int p = 120 + (lane - 56);
            kr[p] = 0; vr[p] = 0;
        }
    }
}

// ---- node_tq: tqb[n][h][128] bf16 = (q x Wd)*scale, zero-padded ----

__global__ __launch_bounds__(256) void node_tq_kernel(
    const float* __restrict__ qnode,
    const float* __restrict__ Wd0, const float* __restrict__ Wd1, const float* __restrict__ Wd2,
    ushort_t* __restrict__ tqb, int N)
{
    __shared__ float4 sWd0[1024];
    __shared__ float4 sWd1[256];
    __shared__ float4 sWd2[64];
    __shared__ float qs[4][FEAT];

    int t = threadIdx.x;
    for (int i = t; i < 1024; i += 256) sWd0[i] = ((const float4*)Wd0)[i];
    if (t < 256) sWd1[t] = ((const float4*)Wd1)[t];
    if (t < 64)  sWd2[t] = ((const float4*)Wd2)[t];
    __syncthreads();

    int lane = t & 63, wid = t >> 6;
    int ngrp = (N + 3) >> 2;
    for (int grp = blockIdx.x; grp < ngrp; grp += gridDim.x) {
        int node = __builtin_amdgcn_readfirstlane(grp * 4 + wid);
        if (node >= N) continue;
        const float* qr = qnode + (size_t)node * FEAT;
        qs[wid][lane] = qr[lane];
        if (lane < FEAT - 64) qs[wid][64 + lane] = qr[64 + lane];
        __builtin_amdgcn_wave_barrier();

        ushort_t* tr = tqb + (size_t)node * 512;
        if (lane < 32) {
            int j = lane;
            float a0 = 0, a1 = 0, a2 = 0, a3 = 0;
            #pragma unroll 8
            for (int i = 0; i < 32; i++) {
                float qi = qs[wid][i];
                float4 w = sWd0[i * 32 + j];
                a0 = fmaf(qi, w.x, a0); a1 = fmaf(qi, w.y, a1);
                a2 = fmaf(qi, w.z, a2); a3 = fmaf(qi, w.w, a3);
            }
            tr[0 * 128 + j] = bf16r(a0 * S_IR0);
            tr[1 * 128 + j] = bf16r(a1 * S_IR0);
            tr[2 * 128 + j] = bf16r(a2 * S_IR0);
            tr[3 * 128 + j] = bf16r(a3 * S_IR0);
        } else if (lane < 48) {
            int j = lane - 32;
            float a[4][3] = {};
            for (int i = 0; i < 16; i++) {
                float4 w = sWd1[i * 16 + j];
                #pragma unroll
                for (int c = 0; c < 3; c++) {
                    float qi = qs[wid][32 + i * 3 + c];
                    a[0][c] = fmaf(qi, w.x, a[0][c]);
                    a[1][c] = fmaf(qi, w.y, a[1][c]);
                    a[2][c] = fmaf(qi, w.z, a[2][c]);
                    a[3][c] = fmaf(qi, w.w, a[3][c]);
                }
            }
            #pragma unroll
            for (int h = 0; h < 4; h++)
                #pragma unroll
                for (int c = 0; c < 3; c++)
                    tr[h * 128 + 32 + j * 3 + c] = bf16r(a[h][c] * S_IR1);
        } else if (lane < 56) {
            int j = lane - 48;
            float a[4][5] = {};
            for (int i = 0; i < 8; i++) {
                float4 w = sWd2[i * 8 + j];
                #pragma unroll
                for (int c = 0; c < 5; c++) {
                    float qi = qs[wid][80 + i * 5 + c];
                    a[0][c] = fmaf(qi, w.x, a[0][c]);
                    a[1][c] = fmaf(qi, w.y, a[1][c]);
                    a[2][c] = fmaf(qi, w.z, a[2][c]);
                    a[3][c] = fmaf(qi, w.w, a[3][c]);
                }
            }
            #pragma unroll
            for (int h = 0; h < 4; h++)
                #pragma unroll
                for (int c = 0; c < 5; c++)
                    tr[h * 128 + 80 + j * 5 + c] = bf16r(a[h][c] * S_IR2);
        } else {
            // zero pads: features 120..127 of each head row
            int r = lane - 56;
            #pragma unroll
            for (int h = 0; h < 4; h++) tr[h * 128 + 120 + r] = 0;
        }
        __builtin_amdgcn_wave_barrier();
    }
}

// ---- edge kernel: per-dst MFMA tiles. S^T[h][e] = tq[h][:]·k[e][:] via
//      mfma_f32_16x16x32_bf16 (A=tq rows m=head, B=k gathers n=edge).
//      C layout: col=lane&15=edge, row=(lane>>4)*4+reg=head  [m89/m120 verified].

__global__ __launch_bounds__(256) void edge_mfma_kernel(
    const ushort_t* __restrict__ tqb, const ushort_t* __restrict__ kb,
    const ushort_t* __restrict__ vb,
    const int* __restrict__ offsets, const int* __restrict__ ssrc,
    float* __restrict__ out, int N)
{
    int lane = threadIdx.x & 63, wid = threadIdx.x >> 6;
    int node = blockIdx.x * 4 + wid;
    if (node >= N) return;
    node = __builtin_amdgcn_readfirstlane(node);
    int m = lane & 15, quad = lane >> 4;

    // A-frags: head rows of tq (zero for m>=4 -> C rows 4..15 are zero, unread)
    short8 afr[4];
    if (m < HCNT) {
        const short8* ap = (const short8*)(tqb + (size_t)node * 512 + m * 128 + quad * 8);
        #pragma unroll
        for (int b = 0; b < 4; b++) afr[b] = ap[b * 4];
    } else {
        #pragma unroll
        for (int b = 0; b < 4; b++) afr[b] = (short8){0,0,0,0,0,0,0,0};
    }

    int beg = offsets[node], end = offsets[node + 1];
    float zpart = 0.0f, accx = 0.0f, accy = 0.0f;
    const uint_t* vrow = (const uint_t*)vb;   // 64 uints per row (2 bf16 each)

    for (int tb = beg; tb < end; tb += 16) {
        int rem = end - tb; if (rem > 16) rem = 16;
        int idx = tb + (m < rem ? m : rem - 1);
        int src = ssrc[idx];
        const short8* bp = (const short8*)(kb + (size_t)src * 128 + quad * 8);
        short8 b0 = bp[0], b1 = bp[4], b2 = bp[8], b3 = bp[12];
        floatx4 C = {0.0f, 0.0f, 0.0f, 0.0f};
        C = __builtin_amdgcn_mfma_f32_16x16x32_bf16(afr[0], b0, C, 0, 0, 0);
        C = __builtin_amdgcn_mfma_f32_16x16x32_bf16(afr[1], b1, C, 0, 0, 0);
        C = __builtin_amdgcn_mfma_f32_16x16x32_bf16(afr[2], b2, C, 0, 0, 0);
        C = __builtin_amdgcn_mfma_f32_16x16x32_bf16(afr[3], b3, C, 0, 0, 0);

        float w = 0.0f;
        if (quad == 0 && m < rem) {
            float ex = 0.25f * (__expf(C[0]) + __expf(C[1]) + __expf(C[2]) + __expf(C[3]));
            zpart += ex;
            w = sqrtf(ex);
        }

        if (rem == 16) {
            #pragma unroll
            for (int e0 = 0; e0 < 16; e0 += 8) {
                float we[8]; int se[8]; uint_t vp[8];
                #pragma unroll
                for (int j = 0; j < 8; j++) {
                    we[j] = __shfl(w, e0 + j, 64);
                    se[j] = __shfl(src, e0 + j, 64);
                }
                #pragma unroll
                for (int j = 0; j < 8; j++) vp[j] = vrow[(size_t)se[j] * 64 + lane];
                #pragma unroll
                for (int j = 0; j < 8; j++) {
                    accx = fmaf(we[j], __uint_as_float(vp[j] << 16), accx);
                    accy = fmaf(we[j], __uint_as_float(vp[j] & 0xffff0000u), accy);
                }
            }
        } else {
            for (int e = 0; e < rem; e++) {
                float we = __shfl(w, e, 64);
                int   se = __shfl(src, e, 64);
                uint_t vp = vrow[(size_t)se * 64 + lane];
                accx = fmaf(we, __uint_as_float(vp << 16), accx);
                accy = fmaf(we, __uint_as_float(vp & 0xffff0000u), accy);
            }
        }
    }

    // zsum: nonzero only on quad0 lanes; xor{1,2,4,8} folds within the 16-group
    zpart += __shfl_xor(zpart, 1, 64);
    zpart += __shfl_xor(zpart, 2, 64);
    zpart += __shfl_xor(zpart, 4, 64);
    zpart += __shfl_xor(zpart, 8, 64);
    float zsum = __shfl(zpart, 0, 64);
    float scale = (zsum > 0.0f) ? rsqrtf(zsum) : 0.0f;

    if (lane < 60) {   // lane owns features {2*lane, 2*lane+1}
        float2* op = (float2*)(out + (size_t)node * FEAT) + lane;
        float2 o = *op;  // pre-written v_node (fp32)
        o.x = fmaf(accx, scale, o.x);
        o.y = fmaf(accy, scale, o.y);
        *op = o;
    }
}

// ---------------- launch ----------------

extern "C" void kernel_launch(void* const* d_in, const int* in_sizes, int n_in,
                              void* d_out, int out_size, void* d_ws, size_t ws_size,
                              hipStream_t stream) {
    const float* x   = (const float*)d_in[0];
    const float* Wq0 = (const float*)d_in[1];
    const float* Wq1 = (const float*)d_in[2];
    const float* Wq2 = (const float*)d_in[3];
    const float* Wk0 = (const float*)d_in[4];
    const float* Wk1 = (const float*)d_in[5];
    const float* Wk2 = (const float*)d_in[6];
    const float* Wv0 = (const float*)d_in[7];
    const float* Wv1 = (const float*)d_in[8];
    const float* Wv2 = (const float*)d_in[9];
    const float* Wd0 = (const float*)d_in[10];
    const float* Wd1 = (const float*)d_in[11];
    const float* Wd2 = (const float*)d_in[12];
    const int* edge_dst = (const int*)d_in[13];
    const int* edge_src = (const int*)d_in[14];
    float* out = (float*)d_out;

    int N = in_sizes[0] / FEAT;
    int E = in_sizes[13];

    float* ws = (float*)d_ws;
    float* qnode = ws;                                    // N*120 f32
    ushort_t* kb  = (ushort_t*)(qnode + (size_t)N * FEAT);// N*128 bf16
    ushort_t* vb  = kb + (size_t)N * 128;                 // N*128 bf16
    ushort_t* tqb = vb + (size_t)N * 128;                 // N*512 bf16
    int* offsets = (int*)(tqb + (size_t)N * 512);         // N+1
    int* cursor  = offsets + (N + 1);                     // N
    int* bsum    = cursor + N;                            // 256
    int* ssrc    = bsum + 256;                            // E

    int NB = (N + 255) / 256;
    int EB = (E + 255) / 256;
    int NW = (N + 3) / 4;

    zero_int_kernel<<<NB, 256, 0, stream>>>(cursor, N);
    hist_kernel<<<EB, 256, 0, stream>>>(edge_dst, cursor, E);
    scan_block_kernel<<<NB, 256, 0, stream>>>(cursor, offsets, bsum, N);
    scan_sums_kernel<<<1, 256, 0, stream>>>(bsum, NB);
    add_offsets_kernel<<<NB, 256, 0, stream>>>(offsets, bsum, cursor, N, E);
    scatter_kernel<<<EB, 256, 0, stream>>>(edge_dst, edge_src, cursor, ssrc, E);

    node_qkv_kernel<<<2048, 256, 0, stream>>>(x, Wq0, Wq1, Wq2, Wk0, Wk1, Wk2,
                                              Wv0, Wv1, Wv2, qnode, kb, vb, out, N);
    node_tq_kernel<<<2048, 256, 0, stream>>>(qnode, Wd0, Wd1, Wd2, tqb, N);
    edge_mfma_kernel<<<NW, 256, 0, stream>>>(tqb, kb, vb, offsets, ssrc, out, N);
}